// Round 9
// baseline (310.476 us; speedup 1.0000x reference)
//
#include <hip/hip_runtime.h>

// LGCN encoder. bf16 propagated embeddings; acc deferred/fused into last layer.
// SpMM: 4 rows per wave (16 lanes/row = 2 groups x 8 lanes), unroll 4 ->
// 8 nnz in flight per row, 32 gathers/wave. pack/ptr loads PLAIN (lines
// shared across rows/waves; NT eviction cost +8MB FETCH, round 7).
// CSR build: direct-scatter binning (no LDS staging: hist -> claim bucket
// window -> pos=atomicAdd scatter; ~16-entry contiguous windows per
// (block,bin) L2-merge fine). aux = {row[] , cv int2[]}; cv IS the pack
// payload. bucket_fused register-batched (<=17 entries/thread).

constexpr int USER_NUM = 50000;
constexpr int ITEM_NUM = 50000;
constexpr int N_NODES  = USER_NUM + ITEM_NUM;   // 100000
constexpr int EMB      = 64;
constexpr int N_LAYERS = 3;
constexpr int TOTAL    = N_NODES * EMB;         // 6,400,000
constexpr int TOTAL4   = TOTAL / 4;
constexpr int U4       = USER_NUM * EMB / 4;

constexpr int RSHIFT = 10;                      // 1024 rows per bucket
constexpr int RB     = 1 << RSHIFT;
constexpr int KA = (N_NODES + RB - 1) / RB;     // 98
constexpr int KS = (USER_NUM + RB - 1) / RB;    // 49
constexpr int NBIN = 128;
constexpr int BCHUNK = 2048;
constexpr int SLOT   = 17408;                   // bucket slot: mean 16384 + 8 sigma
constexpr int PT     = SLOT / RB;               // 17 entries per thread max

__device__ __forceinline__ int   ntl(const int* p)   { return __builtin_nontemporal_load(p); }
__device__ __forceinline__ float ntlf(const float* p){ return __builtin_nontemporal_load(p); }
__device__ __forceinline__ int2  ntl2(const int2* p) {
    unsigned long long u = __builtin_nontemporal_load(
        reinterpret_cast<const unsigned long long*>(p));
    int2 r; r.x = (int)(unsigned)u; r.y = (int)(unsigned)(u >> 32); return r;
}

__device__ __forceinline__ unsigned f2bf(float f) {
    unsigned b = __float_as_uint(f);
    return (b + 0x7fffu + ((b >> 16) & 1u)) >> 16;   // RNE
}
__device__ __forceinline__ void bf2x(unsigned u, float& a, float& b) {
    a = __uint_as_float(u << 16);
    b = __uint_as_float(u & 0xffff0000u);
}

// Binning fused with ego init. Direct scatter: LDS = hist + cursors only
// (2.5KB -> high occupancy). tails are global COUNTS; slot base b*SLOT
// added at write.
__global__ void __launch_bounds__(256) build_and_init(
    const float* __restrict__ user_emb, const float* __restrict__ item_emb,
    unsigned* __restrict__ ego2, int nbin_blocks,
    const int* __restrict__ arows, const int* __restrict__ acols,
    const float* __restrict__ avals, int annz, int nchA, int* __restrict__ tailA,
    int* __restrict__ auxRA, int2* __restrict__ auxCVA,
    const int* __restrict__ srows, const int* __restrict__ scols,
    const float* __restrict__ svals, int snnz, int* __restrict__ tailS,
    int* __restrict__ auxRS, int2* __restrict__ auxCVS)
{
    __shared__ int hcnt[NBIN], hcur[NBIN];

    if ((int)blockIdx.x >= nbin_blocks) {
        int i = (blockIdx.x - nbin_blocks) * 256 + threadIdx.x;
        if (i >= TOTAL4) return;
        float4 v = (i < U4) ? reinterpret_cast<const float4*>(user_emb)[i]
                            : reinterpret_cast<const float4*>(item_emb)[i - U4];
        uint2 o;
        o.x = f2bf(v.x) | (f2bf(v.y) << 16);
        o.y = f2bf(v.z) | (f2bf(v.w) << 16);
        reinterpret_cast<uint2*>(ego2)[i] = o;
        return;
    }

    const int* rows; const int* cols; const float* vals; int nnz; int* tail;
    int* auxR; int2* auxCV; int chunk;
    if ((int)blockIdx.x < nchA) {
        rows = arows; cols = acols; vals = avals; nnz = annz; tail = tailA;
        auxR = auxRA; auxCV = auxCVA; chunk = blockIdx.x;
    } else {
        rows = srows; cols = scols; vals = svals; nnz = snnz; tail = tailS;
        auxR = auxRS; auxCV = auxCVS; chunk = blockIdx.x - nchA;
    }
    int begE = chunk * BCHUNK;
    int cnt = nnz - begE; if (cnt > BCHUNK) cnt = BCHUNK;
    int t = threadIdx.x;
    if (t < NBIN) hcnt[t] = 0;
    __syncthreads();
    int r[8], c[8]; float v[8];
    for (int k = 0; k < 8; ++k) {
        int idx = t + k * 256;
        if (idx < cnt) {
            int e = begE + idx;
            r[k] = ntl(rows + e); c[k] = ntl(cols + e); v[k] = ntlf(vals + e);
            atomicAdd(&hcnt[r[k] >> RSHIFT], 1);
        }
    }
    __syncthreads();
    // claim this block's window in each non-empty bucket; cursor = local base
    if (t < NBIN && hcnt[t] > 0) hcur[t] = atomicAdd(&tail[t], hcnt[t]);
    __syncthreads();
    for (int k = 0; k < 8; ++k) {
        int idx = t + k * 256;
        if (idx < cnt) {
            int b = r[k] >> RSHIFT;
            int pos = atomicAdd(&hcur[b], 1);
            int g = b * SLOT + pos;
            auxR[g]  = r[k];
            auxCV[g] = make_int2(c[k], __float_as_int(v[k]));
        }
    }
}

// One block per 1024-row bucket: computes its own pack-base (wave reduce over
// bucket counts), LDS hist, shuffle scan -> ptr[], counting sort into this
// bucket's private pack window. Register-batched: each thread owns <=PT
// entries; all global loads issued before the LDS-atomic chains.
__global__ void __launch_bounds__(1024) bucket_fused(
    const int* __restrict__ auxRA, const int2* __restrict__ auxCVA,
    const int* __restrict__ tailA,
    int* __restrict__ ptrA, int2* __restrict__ packA,
    const int* __restrict__ auxRS, const int2* __restrict__ auxCVS,
    const int* __restrict__ tailS,
    int* __restrict__ ptrS, int2* __restrict__ packS)
{
    __shared__ int cur[RB];
    __shared__ int wsum[16];
    __shared__ int s_pbase;
    const int* auxR; const int2* auxCV; const int* tail;
    int* ptr; int2* pack; int b; int n; int K;
    if ((int)blockIdx.x < KA) {
        auxR = auxRA; auxCV = auxCVA; tail = tailA;
        ptr = ptrA; pack = packA; b = blockIdx.x; n = N_NODES; K = KA;
    } else {
        auxR = auxRS; auxCV = auxCVS; tail = tailS;
        ptr = ptrS; pack = packS; b = blockIdx.x - KA; n = USER_NUM; K = KS;
    }
    int t = threadIdx.x;
    if (t < 64) {                       // pbase = sum of counts of buckets < b
        int v = (t < b) ? tail[t] : 0;
        if (t + 64 < b) v += tail[t + 64];
        for (int off = 32; off; off >>= 1) v += __shfl_xor(v, off, 64);
        if (t == 0) {
            s_pbase = v;
            if (b == K - 1) ptr[n] = v + tail[b];   // total nnz
        }
    }
    cur[t] = 0;
    __syncthreads();
    int rowbase = b << RSHIFT;
    int nrows = n - rowbase; if (nrows > RB) nrows = RB;
    int cntb = tail[b];
    int segb = b * SLOT, sege = segb + cntb;
    int pbase = s_pbase;

    // ---- pass 1: batched row loads (up to PT outstanding), then atomics ----
    int rv[PT];
#pragma unroll
    for (int k = 0; k < PT; ++k) {
        int id = segb + t + k * RB;
        if (id < sege) rv[k] = ntl(auxR + id) - rowbase;
    }
#pragma unroll
    for (int k = 0; k < PT; ++k) {
        int id = segb + t + k * RB;
        if (id < sege) atomicAdd(&cur[rv[k]], 1);
    }
    __syncthreads();
    int a0 = cur[t];
    // 64-lane inclusive shuffle scan
    int lane = t & 63, wid = t >> 6;
    int s = a0;
    for (int off = 1; off < 64; off <<= 1) {
        int u = __shfl_up(s, off, 64);
        if (lane >= off) s += u;
    }
    if (lane == 63) wsum[wid] = s;
    __syncthreads();
    if (wid == 0) {
        int w = (lane < 16) ? wsum[lane] : 0;
        for (int off = 1; off < 16; off <<= 1) {
            int u = __shfl_up(w, off, 64);
            if (lane >= off) w += u;
        }
        if (lane < 16) wsum[lane] = w;
    }
    __syncthreads();
    int wbase = (wid > 0) ? wsum[wid - 1] : 0;
    int base = pbase + wbase + s - a0;       // exclusive prefix + pack base
    cur[t] = base;
    if (t < nrows) ptr[rowbase + t] = base;
    __syncthreads();

    // ---- pass 2: batched cv loads (rows already in regs), scatter ----
    int2 cv[PT];
#pragma unroll
    for (int k = 0; k < PT; ++k) {
        int id = segb + t + k * RB;
        if (id < sege) cv[k] = ntl2(auxCV + id);
    }
#pragma unroll
    for (int k = 0; k < PT; ++k) {
        int id = segb + t + k * RB;
        if (id < sege) {
            int pos = atomicAdd(&cur[rv[k]], 1);
            pack[pos] = cv[k];
        }
    }
}

__device__ __forceinline__ void gacc(float (&acc)[8], float v, uint4 u) {
    float f0, f1, f2, f3, f4, f5, f6, f7;
    bf2x(u.x, f0, f1); bf2x(u.y, f2, f3); bf2x(u.z, f4, f5); bf2x(u.w, f6, f7);
    acc[0] += v * f0; acc[1] += v * f1; acc[2] += v * f2; acc[3] += v * f3;
    acc[4] += v * f4; acc[5] += v * f5; acc[6] += v * f6; acc[7] += v * f7;
}
__device__ __forceinline__ uint4 pack8(const float (&acc)[8]) {
    uint4 o;
    o.x = f2bf(acc[0]) | (f2bf(acc[1]) << 16);
    o.y = f2bf(acc[2]) | (f2bf(acc[3]) << 16);
    o.z = f2bf(acc[4]) | (f2bf(acc[5]) << 16);
    o.w = f2bf(acc[6]) | (f2bf(acc[7]) << 16);
    return o;
}

// hu = u + S*u. 4 rows/wave; unroll 4 -> 8 gathers in flight per row.
__global__ void __launch_bounds__(256) spmm_s(
    const int* __restrict__ ptr, const int2* __restrict__ pack,
    const uint4* __restrict__ ego8, uint4* __restrict__ hu8)
{
    int lane = threadIdx.x & 63;
    int g = (lane >> 3) & 1;
    int li = lane & 7;
    int r = blockIdx.x * 16 + (threadIdx.x >> 6) * 4 + (lane >> 4);
    int beg = 0, end = 0;
    if (r < USER_NUM) { beg = ptr[r]; end = ptr[r + 1]; }
    float acc[8] = {0, 0, 0, 0, 0, 0, 0, 0};
    int j = beg + g;
    for (; j + 6 < end; j += 8) {
        int2 p0 = pack[j];
        int2 p1 = pack[j + 2];
        int2 p2 = pack[j + 4];
        int2 p3 = pack[j + 6];
        uint4 x0 = ego8[p0.x * 8 + li];
        uint4 x1 = ego8[p1.x * 8 + li];
        uint4 x2 = ego8[p2.x * 8 + li];
        uint4 x3 = ego8[p3.x * 8 + li];
        gacc(acc, __int_as_float(p0.y), x0);
        gacc(acc, __int_as_float(p1.y), x1);
        gacc(acc, __int_as_float(p2.y), x2);
        gacc(acc, __int_as_float(p3.y), x3);
    }
    for (; j + 2 < end; j += 4) {
        int2 p0 = pack[j];
        int2 p1 = pack[j + 2];
        uint4 x0 = ego8[p0.x * 8 + li];
        uint4 x1 = ego8[p1.x * 8 + li];
        gacc(acc, __int_as_float(p0.y), x0);
        gacc(acc, __int_as_float(p1.y), x1);
    }
    if (j < end) {
        int2 p = pack[j];
        gacc(acc, __int_as_float(p.y), ego8[p.x * 8 + li]);
    }
#pragma unroll
    for (int k = 0; k < 8; ++k) acc[k] += __shfl_xor(acc[k], 8, 64);
    if (g == 0 && r < USER_NUM) {
        uint4 e = ego8[r * 8 + li];
        float f0, f1;
        bf2x(e.x, f0, f1); acc[0] += f0; acc[1] += f1;
        bf2x(e.y, f0, f1); acc[2] += f0; acc[3] += f1;
        bf2x(e.z, f0, f1); acc[4] += f0; acc[5] += f1;
        bf2x(e.w, f0, f1); acc[6] += f0; acc[7] += f1;
        hu8[r * 8 + li] = pack8(acc);
    }
}

// next = A*h (h = hu for user cols, ego for item cols). Unroll 4. LAST layer
// fuses the final sum: acc_out = (input_f32 + e1 + e2 + this_layer_f32)*0.25.
template <bool LAST>
__global__ void __launch_bounds__(256) spmm_adj(
    const int* __restrict__ ptr, const int2* __restrict__ pack,
    const uint4* __restrict__ hu8, const uint4* __restrict__ ego8,
    uint4* __restrict__ next8,
    const uint4* __restrict__ e1, const uint4* __restrict__ e2,
    const float* __restrict__ user_emb, const float* __restrict__ item_emb,
    float* __restrict__ accOut)
{
    int lane = threadIdx.x & 63;
    int g = (lane >> 3) & 1;
    int li = lane & 7;
    int r = blockIdx.x * 16 + (threadIdx.x >> 6) * 4 + (lane >> 4);
    int beg = 0, end = 0;
    if (r < N_NODES) { beg = ptr[r]; end = ptr[r + 1]; }
    float acc[8] = {0, 0, 0, 0, 0, 0, 0, 0};
    int j = beg + g;
    for (; j + 6 < end; j += 8) {
        int2 p0 = pack[j];
        int2 p1 = pack[j + 2];
        int2 p2 = pack[j + 4];
        int2 p3 = pack[j + 6];
        uint4 x0 = (p0.x < USER_NUM) ? hu8[p0.x * 8 + li] : ego8[p0.x * 8 + li];
        uint4 x1 = (p1.x < USER_NUM) ? hu8[p1.x * 8 + li] : ego8[p1.x * 8 + li];
        uint4 x2 = (p2.x < USER_NUM) ? hu8[p2.x * 8 + li] : ego8[p2.x * 8 + li];
        uint4 x3 = (p3.x < USER_NUM) ? hu8[p3.x * 8 + li] : ego8[p3.x * 8 + li];
        gacc(acc, __int_as_float(p0.y), x0);
        gacc(acc, __int_as_float(p1.y), x1);
        gacc(acc, __int_as_float(p2.y), x2);
        gacc(acc, __int_as_float(p3.y), x3);
    }
    for (; j + 2 < end; j += 4) {
        int2 p0 = pack[j];
        int2 p1 = pack[j + 2];
        uint4 x0 = (p0.x < USER_NUM) ? hu8[p0.x * 8 + li] : ego8[p0.x * 8 + li];
        uint4 x1 = (p1.x < USER_NUM) ? hu8[p1.x * 8 + li] : ego8[p1.x * 8 + li];
        gacc(acc, __int_as_float(p0.y), x0);
        gacc(acc, __int_as_float(p1.y), x1);
    }
    if (j < end) {
        int2 p = pack[j];
        uint4 x = (p.x < USER_NUM) ? hu8[p.x * 8 + li] : ego8[p.x * 8 + li];
        gacc(acc, __int_as_float(p.y), x);
    }
#pragma unroll
    for (int k = 0; k < 8; ++k) acc[k] += __shfl_xor(acc[k], 8, 64);
    if (g == 0 && r < N_NODES) {
        if (!LAST) {
            next8[r * 8 + li] = pack8(acc);
        } else {
            const float4* inp; int base;
            if (r < USER_NUM) {
                inp = reinterpret_cast<const float4*>(user_emb);
                base = r * 16 + li * 2;
            } else {
                inp = reinterpret_cast<const float4*>(item_emb);
                base = (r - USER_NUM) * 16 + li * 2;
            }
            float4 v0 = inp[base], v1 = inp[base + 1];
            uint4 a = e1[r * 8 + li];
            uint4 b = e2[r * 8 + li];
            float f0, f1;
            bf2x(a.x, f0, f1); v0.x += f0; v0.y += f1;
            bf2x(a.y, f0, f1); v0.z += f0; v0.w += f1;
            bf2x(a.z, f0, f1); v1.x += f0; v1.y += f1;
            bf2x(a.w, f0, f1); v1.z += f0; v1.w += f1;
            bf2x(b.x, f0, f1); v0.x += f0; v0.y += f1;
            bf2x(b.y, f0, f1); v0.z += f0; v0.w += f1;
            bf2x(b.z, f0, f1); v1.x += f0; v1.y += f1;
            bf2x(b.w, f0, f1); v1.z += f0; v1.w += f1;
            v0.x = (v0.x + acc[0]) * 0.25f; v0.y = (v0.y + acc[1]) * 0.25f;
            v0.z = (v0.z + acc[2]) * 0.25f; v0.w = (v0.w + acc[3]) * 0.25f;
            v1.x = (v1.x + acc[4]) * 0.25f; v1.y = (v1.y + acc[5]) * 0.25f;
            v1.z = (v1.z + acc[6]) * 0.25f; v1.w = (v1.w + acc[7]) * 0.25f;
            float4* op = reinterpret_cast<float4*>(accOut);
            op[r * 16 + li * 2]     = v0;
            op[r * 16 + li * 2 + 1] = v1;
        }
    }
}

extern "C" void kernel_launch(void* const* d_in, const int* in_sizes, int n_in,
                              void* d_out, int out_size, void* d_ws, size_t ws_size,
                              hipStream_t stream) {
    const float* user_emb = (const float*)d_in[0];
    const float* item_emb = (const float*)d_in[1];
    const int*   adj_rows = (const int*)d_in[2];
    const int*   adj_cols = (const int*)d_in[3];
    const float* adj_vals = (const float*)d_in[4];
    const int*   s_rows   = (const int*)d_in[5];
    const int*   s_cols   = (const int*)d_in[6];
    const float* s_vals   = (const float*)d_in[7];
    const int adj_nnz = in_sizes[2];
    const int s_nnz   = in_sizes[5];

    float* acc = (float*)d_out;

    char* p = (char*)d_ws;
    auto alloc = [&](size_t bytes) { void* q = p; p += (bytes + 255) & ~(size_t)255; return q; };
    unsigned* egoA = (unsigned*)alloc((size_t)TOTAL * 2);
    unsigned* egoB = (unsigned*)alloc((size_t)TOTAL * 2);
    unsigned* egoC = (unsigned*)alloc((size_t)TOTAL * 2);
    unsigned* hu   = (unsigned*)alloc((size_t)USER_NUM * EMB * 2);
    int*   ptrA  = (int*)alloc((size_t)(N_NODES + 1) * 4);
    int2*  packA = (int2*)alloc((size_t)adj_nnz * 8);
    int*   ptrS  = (int*)alloc((size_t)(USER_NUM + 1) * 4);
    int2*  packS = (int2*)alloc((size_t)s_nnz * 8);
    int*   auxRA  = (int*)alloc((size_t)KA * SLOT * 4);
    int2*  auxCVA = (int2*)alloc((size_t)KA * SLOT * 8);
    int*   auxRS  = (int*)alloc((size_t)KS * SLOT * 4);
    int2*  auxCVS = (int2*)alloc((size_t)KS * SLOT * 8);
    int*   tails = (int*)alloc(2 * NBIN * 4);
    int*   tailA = tails;
    int*   tailS = tails + NBIN;

    const int BLK = 256;
    const int ew_grid = (TOTAL4 + BLK - 1) / BLK;
    const int nchA = (adj_nnz + BCHUNK - 1) / BCHUNK;
    const int nchS = (s_nnz + BCHUNK - 1) / BCHUNK;
    const int nbin_blocks = nchA + nchS;

    // ---- CSR build (fused with ego init) ----
    hipMemsetAsync(tails, 0, 2 * NBIN * sizeof(int), stream);
    build_and_init<<<nbin_blocks + ew_grid, 256, 0, stream>>>(
        user_emb, item_emb, egoA, nbin_blocks,
        adj_rows, adj_cols, adj_vals, adj_nnz, nchA, tailA, auxRA, auxCVA,
        s_rows, s_cols, s_vals, s_nnz, tailS, auxRS, auxCVS);
    bucket_fused<<<KA + KS, 1024, 0, stream>>>(
        auxRA, auxCVA, tailA, ptrA, packA,
        auxRS, auxCVS, tailS, ptrS, packS);

    unsigned* bufs[3] = {egoA, egoB, egoC};
    const int s_grid   = (USER_NUM + 15) / 16;
    const int adj_grid = (N_NODES + 15) / 16;

    for (int l = 0; l < N_LAYERS; ++l) {
        unsigned* in  = bufs[l % 3];
        unsigned* out = bufs[(l + 1) % 3];
        spmm_s<<<s_grid, BLK, 0, stream>>>(ptrS, packS, (const uint4*)in, (uint4*)hu);
        if (l < N_LAYERS - 1) {
            spmm_adj<false><<<adj_grid, BLK, 0, stream>>>(
                ptrA, packA, (const uint4*)hu, (const uint4*)in, (uint4*)out,
                nullptr, nullptr, nullptr, nullptr, nullptr);
        } else {
            // e1 = egoB (layer-0 out), e2 = egoC (layer-1 out); e3 kept in f32
            // accumulators and fused straight into the final average.
            spmm_adj<true><<<adj_grid, BLK, 0, stream>>>(
                ptrA, packA, (const uint4*)hu, (const uint4*)in, nullptr,
                (const uint4*)egoB, (const uint4*)egoC, user_emb, item_emb, acc);
        }
    }
}

// Round 10
// 295.291 us; speedup vs baseline: 1.0514x; 1.0514x over previous
//
#include <hip/hip_runtime.h>

// LGCN encoder. bf16 propagated embeddings; acc deferred/fused into last layer.
// SpMM: 4 rows per wave (16 lanes/row = 2 groups x 8 lanes), unroll 4 ->
// 8 nnz in flight per row, 32 gathers/wave. pack/ptr loads PLAIN (lines
// shared across rows/waves; NT eviction cost +8MB FETCH, round 7).
// CSR build: LDS-staged binning (stage-and-flush keeps aux writes coalesced;
// direct scatter cost 3x write amplification, round 9) fused with ego init;
// wave-parallel 128-bin scan + overlapped tail-claim. aux = {row[], cv int2[]}
// (cv IS the pack payload). bucket_fused register-batched (<=17/thread).

constexpr int USER_NUM = 50000;
constexpr int ITEM_NUM = 50000;
constexpr int N_NODES  = USER_NUM + ITEM_NUM;   // 100000
constexpr int EMB      = 64;
constexpr int N_LAYERS = 3;
constexpr int TOTAL    = N_NODES * EMB;         // 6,400,000
constexpr int TOTAL4   = TOTAL / 4;
constexpr int U4       = USER_NUM * EMB / 4;

constexpr int RSHIFT = 10;                      // 1024 rows per bucket
constexpr int RB     = 1 << RSHIFT;
constexpr int KA = (N_NODES + RB - 1) / RB;     // 98
constexpr int KS = (USER_NUM + RB - 1) / RB;    // 49
constexpr int NBIN = 128;
constexpr int BCHUNK = 2048;
constexpr int SLOT   = 17408;                   // bucket slot: mean 16384 + 8 sigma
constexpr int PT     = SLOT / RB;               // 17 entries per thread max

__device__ __forceinline__ int   ntl(const int* p)   { return __builtin_nontemporal_load(p); }
__device__ __forceinline__ float ntlf(const float* p){ return __builtin_nontemporal_load(p); }
__device__ __forceinline__ int2  ntl2(const int2* p) {
    unsigned long long u = __builtin_nontemporal_load(
        reinterpret_cast<const unsigned long long*>(p));
    int2 r; r.x = (int)(unsigned)u; r.y = (int)(unsigned)(u >> 32); return r;
}

__device__ __forceinline__ unsigned f2bf(float f) {
    unsigned b = __float_as_uint(f);
    return (b + 0x7fffu + ((b >> 16) & 1u)) >> 16;   // RNE
}
__device__ __forceinline__ void bf2x(unsigned u, float& a, float& b) {
    a = __uint_as_float(u << 16);
    b = __uint_as_float(u & 0xffff0000u);
}

// Binning (tails are COUNTS; slot base b*SLOT added at write) fused with
// ego init (blocks >= nbin_blocks convert fp32 inputs -> bf16 ego).
__global__ void __launch_bounds__(256) build_and_init(
    const float* __restrict__ user_emb, const float* __restrict__ item_emb,
    unsigned* __restrict__ ego2, int nbin_blocks,
    const int* __restrict__ arows, const int* __restrict__ acols,
    const float* __restrict__ avals, int annz, int nchA, int* __restrict__ tailA,
    int* __restrict__ auxRA, int2* __restrict__ auxCVA,
    const int* __restrict__ srows, const int* __restrict__ scols,
    const float* __restrict__ svals, int snnz, int* __restrict__ tailS,
    int* __restrict__ auxRS, int2* __restrict__ auxCVS)
{
    __shared__ int hcnt[NBIN], hoff[NBIN], hcur[NBIN], hbase[NBIN];
    __shared__ int sR[BCHUNK], sC[BCHUNK];
    __shared__ float sV[BCHUNK];

    if ((int)blockIdx.x >= nbin_blocks) {
        int i = (blockIdx.x - nbin_blocks) * 256 + threadIdx.x;
        if (i >= TOTAL4) return;
        float4 v = (i < U4) ? reinterpret_cast<const float4*>(user_emb)[i]
                            : reinterpret_cast<const float4*>(item_emb)[i - U4];
        uint2 o;
        o.x = f2bf(v.x) | (f2bf(v.y) << 16);
        o.y = f2bf(v.z) | (f2bf(v.w) << 16);
        reinterpret_cast<uint2*>(ego2)[i] = o;
        return;
    }

    const int* rows; const int* cols; const float* vals; int nnz; int* tail;
    int* auxR; int2* auxCV; int chunk;
    if ((int)blockIdx.x < nchA) {
        rows = arows; cols = acols; vals = avals; nnz = annz; tail = tailA;
        auxR = auxRA; auxCV = auxCVA; chunk = blockIdx.x;
    } else {
        rows = srows; cols = scols; vals = svals; nnz = snnz; tail = tailS;
        auxR = auxRS; auxCV = auxCVS; chunk = blockIdx.x - nchA;
    }
    int begE = chunk * BCHUNK;
    int cnt = nnz - begE; if (cnt > BCHUNK) cnt = BCHUNK;
    int t = threadIdx.x;
    if (t < NBIN) hcnt[t] = 0;
    __syncthreads();
    int r[8], c[8]; float v[8];
    for (int k = 0; k < 8; ++k) {
        int idx = t + k * 256;
        if (idx < cnt) {
            int e = begE + idx;
            r[k] = ntl(rows + e); c[k] = ntl(cols + e); v[k] = ntlf(vals + e);
            atomicAdd(&hcnt[r[k] >> RSHIFT], 1);
        }
    }
    __syncthreads();
    // wave 0: parallel exclusive scan of 128 bins (2 per lane);
    // threads 128..255: concurrent per-bin global tail claim.
    if (t < 64) {
        int a  = hcnt[t];
        int bq = hcnt[t + 64];
        int sa = a, sb = bq;
        for (int off = 1; off < 64; off <<= 1) {
            int ua = __shfl_up(sa, off, 64);
            int ub = __shfl_up(sb, off, 64);
            if (t >= off) { sa += ua; sb += ub; }
        }
        int ta = __shfl(sa, 63, 64);      // total of bins 0..63
        hoff[t] = sa - a;        hcur[t] = sa - a;
        hoff[t + 64] = ta + sb - bq;  hcur[t + 64] = ta + sb - bq;
    } else if (t >= 128) {
        int bb = t - 128;                 // NBIN == 128
        if (hcnt[bb] > 0) hbase[bb] = atomicAdd(&tail[bb], hcnt[bb]);
    }
    __syncthreads();
    for (int k = 0; k < 8; ++k) {
        int idx = t + k * 256;
        if (idx < cnt) {
            int b = r[k] >> RSHIFT;
            int pos = atomicAdd(&hcur[b], 1);
            sR[pos] = r[k]; sC[pos] = c[k]; sV[pos] = v[k];
        }
    }
    __syncthreads();
    // coalesced flush: consecutive idx -> consecutive g within each bin run
    for (int idx = t; idx < cnt; idx += 256) {
        int rr = sR[idx];
        int b = rr >> RSHIFT;
        int g = b * SLOT + hbase[b] + (idx - hoff[b]);
        auxR[g]  = rr;
        auxCV[g] = make_int2(sC[idx], __float_as_int(sV[idx]));
    }
}

// One block per 1024-row bucket: computes its own pack-base (wave reduce over
// bucket counts), LDS hist, shuffle scan -> ptr[], counting sort into this
// bucket's private pack window. Register-batched: each thread owns <=PT
// entries; all global loads issued before the LDS-atomic chains.
__global__ void __launch_bounds__(1024) bucket_fused(
    const int* __restrict__ auxRA, const int2* __restrict__ auxCVA,
    const int* __restrict__ tailA,
    int* __restrict__ ptrA, int2* __restrict__ packA,
    const int* __restrict__ auxRS, const int2* __restrict__ auxCVS,
    const int* __restrict__ tailS,
    int* __restrict__ ptrS, int2* __restrict__ packS)
{
    __shared__ int cur[RB];
    __shared__ int wsum[16];
    __shared__ int s_pbase;
    const int* auxR; const int2* auxCV; const int* tail;
    int* ptr; int2* pack; int b; int n; int K;
    if ((int)blockIdx.x < KA) {
        auxR = auxRA; auxCV = auxCVA; tail = tailA;
        ptr = ptrA; pack = packA; b = blockIdx.x; n = N_NODES; K = KA;
    } else {
        auxR = auxRS; auxCV = auxCVS; tail = tailS;
        ptr = ptrS; pack = packS; b = blockIdx.x - KA; n = USER_NUM; K = KS;
    }
    int t = threadIdx.x;
    if (t < 64) {                       // pbase = sum of counts of buckets < b
        int v = (t < b) ? tail[t] : 0;
        if (t + 64 < b) v += tail[t + 64];
        for (int off = 32; off; off >>= 1) v += __shfl_xor(v, off, 64);
        if (t == 0) {
            s_pbase = v;
            if (b == K - 1) ptr[n] = v + tail[b];   // total nnz
        }
    }
    cur[t] = 0;
    __syncthreads();
    int rowbase = b << RSHIFT;
    int nrows = n - rowbase; if (nrows > RB) nrows = RB;
    int cntb = tail[b];
    int segb = b * SLOT, sege = segb + cntb;
    int pbase = s_pbase;

    // ---- pass 1: batched row loads (up to PT outstanding), then atomics ----
    int rv[PT];
#pragma unroll
    for (int k = 0; k < PT; ++k) {
        int id = segb + t + k * RB;
        if (id < sege) rv[k] = ntl(auxR + id) - rowbase;
    }
#pragma unroll
    for (int k = 0; k < PT; ++k) {
        int id = segb + t + k * RB;
        if (id < sege) atomicAdd(&cur[rv[k]], 1);
    }
    __syncthreads();
    int a0 = cur[t];
    // 64-lane inclusive shuffle scan
    int lane = t & 63, wid = t >> 6;
    int s = a0;
    for (int off = 1; off < 64; off <<= 1) {
        int u = __shfl_up(s, off, 64);
        if (lane >= off) s += u;
    }
    if (lane == 63) wsum[wid] = s;
    __syncthreads();
    if (wid == 0) {
        int w = (lane < 16) ? wsum[lane] : 0;
        for (int off = 1; off < 16; off <<= 1) {
            int u = __shfl_up(w, off, 64);
            if (lane >= off) w += u;
        }
        if (lane < 16) wsum[lane] = w;
    }
    __syncthreads();
    int wbase = (wid > 0) ? wsum[wid - 1] : 0;
    int base = pbase + wbase + s - a0;       // exclusive prefix + pack base
    cur[t] = base;
    if (t < nrows) ptr[rowbase + t] = base;
    __syncthreads();

    // ---- pass 2: batched cv loads (rows already in regs), scatter ----
    int2 cv[PT];
#pragma unroll
    for (int k = 0; k < PT; ++k) {
        int id = segb + t + k * RB;
        if (id < sege) cv[k] = ntl2(auxCV + id);
    }
#pragma unroll
    for (int k = 0; k < PT; ++k) {
        int id = segb + t + k * RB;
        if (id < sege) {
            int pos = atomicAdd(&cur[rv[k]], 1);
            pack[pos] = cv[k];
        }
    }
}

__device__ __forceinline__ void gacc(float (&acc)[8], float v, uint4 u) {
    float f0, f1, f2, f3, f4, f5, f6, f7;
    bf2x(u.x, f0, f1); bf2x(u.y, f2, f3); bf2x(u.z, f4, f5); bf2x(u.w, f6, f7);
    acc[0] += v * f0; acc[1] += v * f1; acc[2] += v * f2; acc[3] += v * f3;
    acc[4] += v * f4; acc[5] += v * f5; acc[6] += v * f6; acc[7] += v * f7;
}
__device__ __forceinline__ uint4 pack8(const float (&acc)[8]) {
    uint4 o;
    o.x = f2bf(acc[0]) | (f2bf(acc[1]) << 16);
    o.y = f2bf(acc[2]) | (f2bf(acc[3]) << 16);
    o.z = f2bf(acc[4]) | (f2bf(acc[5]) << 16);
    o.w = f2bf(acc[6]) | (f2bf(acc[7]) << 16);
    return o;
}

// hu = u + S*u. 4 rows/wave; unroll 4 -> 8 gathers in flight per row.
__global__ void __launch_bounds__(256) spmm_s(
    const int* __restrict__ ptr, const int2* __restrict__ pack,
    const uint4* __restrict__ ego8, uint4* __restrict__ hu8)
{
    int lane = threadIdx.x & 63;
    int g = (lane >> 3) & 1;
    int li = lane & 7;
    int r = blockIdx.x * 16 + (threadIdx.x >> 6) * 4 + (lane >> 4);
    int beg = 0, end = 0;
    if (r < USER_NUM) { beg = ptr[r]; end = ptr[r + 1]; }
    float acc[8] = {0, 0, 0, 0, 0, 0, 0, 0};
    int j = beg + g;
    for (; j + 6 < end; j += 8) {
        int2 p0 = pack[j];
        int2 p1 = pack[j + 2];
        int2 p2 = pack[j + 4];
        int2 p3 = pack[j + 6];
        uint4 x0 = ego8[p0.x * 8 + li];
        uint4 x1 = ego8[p1.x * 8 + li];
        uint4 x2 = ego8[p2.x * 8 + li];
        uint4 x3 = ego8[p3.x * 8 + li];
        gacc(acc, __int_as_float(p0.y), x0);
        gacc(acc, __int_as_float(p1.y), x1);
        gacc(acc, __int_as_float(p2.y), x2);
        gacc(acc, __int_as_float(p3.y), x3);
    }
    for (; j + 2 < end; j += 4) {
        int2 p0 = pack[j];
        int2 p1 = pack[j + 2];
        uint4 x0 = ego8[p0.x * 8 + li];
        uint4 x1 = ego8[p1.x * 8 + li];
        gacc(acc, __int_as_float(p0.y), x0);
        gacc(acc, __int_as_float(p1.y), x1);
    }
    if (j < end) {
        int2 p = pack[j];
        gacc(acc, __int_as_float(p.y), ego8[p.x * 8 + li]);
    }
#pragma unroll
    for (int k = 0; k < 8; ++k) acc[k] += __shfl_xor(acc[k], 8, 64);
    if (g == 0 && r < USER_NUM) {
        uint4 e = ego8[r * 8 + li];
        float f0, f1;
        bf2x(e.x, f0, f1); acc[0] += f0; acc[1] += f1;
        bf2x(e.y, f0, f1); acc[2] += f0; acc[3] += f1;
        bf2x(e.z, f0, f1); acc[4] += f0; acc[5] += f1;
        bf2x(e.w, f0, f1); acc[6] += f0; acc[7] += f1;
        hu8[r * 8 + li] = pack8(acc);
    }
}

// next = A*h (h = hu for user cols, ego for item cols). Unroll 4. LAST layer
// fuses the final sum: acc_out = (input_f32 + e1 + e2 + this_layer_f32)*0.25.
template <bool LAST>
__global__ void __launch_bounds__(256) spmm_adj(
    const int* __restrict__ ptr, const int2* __restrict__ pack,
    const uint4* __restrict__ hu8, const uint4* __restrict__ ego8,
    uint4* __restrict__ next8,
    const uint4* __restrict__ e1, const uint4* __restrict__ e2,
    const float* __restrict__ user_emb, const float* __restrict__ item_emb,
    float* __restrict__ accOut)
{
    int lane = threadIdx.x & 63;
    int g = (lane >> 3) & 1;
    int li = lane & 7;
    int r = blockIdx.x * 16 + (threadIdx.x >> 6) * 4 + (lane >> 4);
    int beg = 0, end = 0;
    if (r < N_NODES) { beg = ptr[r]; end = ptr[r + 1]; }
    float acc[8] = {0, 0, 0, 0, 0, 0, 0, 0};
    int j = beg + g;
    for (; j + 6 < end; j += 8) {
        int2 p0 = pack[j];
        int2 p1 = pack[j + 2];
        int2 p2 = pack[j + 4];
        int2 p3 = pack[j + 6];
        uint4 x0 = (p0.x < USER_NUM) ? hu8[p0.x * 8 + li] : ego8[p0.x * 8 + li];
        uint4 x1 = (p1.x < USER_NUM) ? hu8[p1.x * 8 + li] : ego8[p1.x * 8 + li];
        uint4 x2 = (p2.x < USER_NUM) ? hu8[p2.x * 8 + li] : ego8[p2.x * 8 + li];
        uint4 x3 = (p3.x < USER_NUM) ? hu8[p3.x * 8 + li] : ego8[p3.x * 8 + li];
        gacc(acc, __int_as_float(p0.y), x0);
        gacc(acc, __int_as_float(p1.y), x1);
        gacc(acc, __int_as_float(p2.y), x2);
        gacc(acc, __int_as_float(p3.y), x3);
    }
    for (; j + 2 < end; j += 4) {
        int2 p0 = pack[j];
        int2 p1 = pack[j + 2];
        uint4 x0 = (p0.x < USER_NUM) ? hu8[p0.x * 8 + li] : ego8[p0.x * 8 + li];
        uint4 x1 = (p1.x < USER_NUM) ? hu8[p1.x * 8 + li] : ego8[p1.x * 8 + li];
        gacc(acc, __int_as_float(p0.y), x0);
        gacc(acc, __int_as_float(p1.y), x1);
    }
    if (j < end) {
        int2 p = pack[j];
        uint4 x = (p.x < USER_NUM) ? hu8[p.x * 8 + li] : ego8[p.x * 8 + li];
        gacc(acc, __int_as_float(p.y), x);
    }
#pragma unroll
    for (int k = 0; k < 8; ++k) acc[k] += __shfl_xor(acc[k], 8, 64);
    if (g == 0 && r < N_NODES) {
        if (!LAST) {
            next8[r * 8 + li] = pack8(acc);
        } else {
            const float4* inp; int base;
            if (r < USER_NUM) {
                inp = reinterpret_cast<const float4*>(user_emb);
                base = r * 16 + li * 2;
            } else {
                inp = reinterpret_cast<const float4*>(item_emb);
                base = (r - USER_NUM) * 16 + li * 2;
            }
            float4 v0 = inp[base], v1 = inp[base + 1];
            uint4 a = e1[r * 8 + li];
            uint4 b = e2[r * 8 + li];
            float f0, f1;
            bf2x(a.x, f0, f1); v0.x += f0; v0.y += f1;
            bf2x(a.y, f0, f1); v0.z += f0; v0.w += f1;
            bf2x(a.z, f0, f1); v1.x += f0; v1.y += f1;
            bf2x(a.w, f0, f1); v1.z += f0; v1.w += f1;
            bf2x(b.x, f0, f1); v0.x += f0; v0.y += f1;
            bf2x(b.y, f0, f1); v0.z += f0; v0.w += f1;
            bf2x(b.z, f0, f1); v1.x += f0; v1.y += f1;
            bf2x(b.w, f0, f1); v1.z += f0; v1.w += f1;
            v0.x = (v0.x + acc[0]) * 0.25f; v0.y = (v0.y + acc[1]) * 0.25f;
            v0.z = (v0.z + acc[2]) * 0.25f; v0.w = (v0.w + acc[3]) * 0.25f;
            v1.x = (v1.x + acc[4]) * 0.25f; v1.y = (v1.y + acc[5]) * 0.25f;
            v1.z = (v1.z + acc[6]) * 0.25f; v1.w = (v1.w + acc[7]) * 0.25f;
            float4* op = reinterpret_cast<float4*>(accOut);
            op[r * 16 + li * 2]     = v0;
            op[r * 16 + li * 2 + 1] = v1;
        }
    }
}

extern "C" void kernel_launch(void* const* d_in, const int* in_sizes, int n_in,
                              void* d_out, int out_size, void* d_ws, size_t ws_size,
                              hipStream_t stream) {
    const float* user_emb = (const float*)d_in[0];
    const float* item_emb = (const float*)d_in[1];
    const int*   adj_rows = (const int*)d_in[2];
    const int*   adj_cols = (const int*)d_in[3];
    const float* adj_vals = (const float*)d_in[4];
    const int*   s_rows   = (const int*)d_in[5];
    const int*   s_cols   = (const int*)d_in[6];
    const float* s_vals   = (const float*)d_in[7];
    const int adj_nnz = in_sizes[2];
    const int s_nnz   = in_sizes[5];

    float* acc = (float*)d_out;

    char* p = (char*)d_ws;
    auto alloc = [&](size_t bytes) { void* q = p; p += (bytes + 255) & ~(size_t)255; return q; };
    unsigned* egoA = (unsigned*)alloc((size_t)TOTAL * 2);
    unsigned* egoB = (unsigned*)alloc((size_t)TOTAL * 2);
    unsigned* egoC = (unsigned*)alloc((size_t)TOTAL * 2);
    unsigned* hu   = (unsigned*)alloc((size_t)USER_NUM * EMB * 2);
    int*   ptrA  = (int*)alloc((size_t)(N_NODES + 1) * 4);
    int2*  packA = (int2*)alloc((size_t)adj_nnz * 8);
    int*   ptrS  = (int*)alloc((size_t)(USER_NUM + 1) * 4);
    int2*  packS = (int2*)alloc((size_t)s_nnz * 8);
    int*   auxRA  = (int*)alloc((size_t)KA * SLOT * 4);
    int2*  auxCVA = (int2*)alloc((size_t)KA * SLOT * 8);
    int*   auxRS  = (int*)alloc((size_t)KS * SLOT * 4);
    int2*  auxCVS = (int2*)alloc((size_t)KS * SLOT * 8);
    int*   tails = (int*)alloc(2 * NBIN * 4);
    int*   tailA = tails;
    int*   tailS = tails + NBIN;

    const int BLK = 256;
    const int ew_grid = (TOTAL4 + BLK - 1) / BLK;
    const int nchA = (adj_nnz + BCHUNK - 1) / BCHUNK;
    const int nchS = (s_nnz + BCHUNK - 1) / BCHUNK;
    const int nbin_blocks = nchA + nchS;

    // ---- CSR build (fused with ego init) ----
    hipMemsetAsync(tails, 0, 2 * NBIN * sizeof(int), stream);
    build_and_init<<<nbin_blocks + ew_grid, 256, 0, stream>>>(
        user_emb, item_emb, egoA, nbin_blocks,
        adj_rows, adj_cols, adj_vals, adj_nnz, nchA, tailA, auxRA, auxCVA,
        s_rows, s_cols, s_vals, s_nnz, tailS, auxRS, auxCVS);
    bucket_fused<<<KA + KS, 1024, 0, stream>>>(
        auxRA, auxCVA, tailA, ptrA, packA,
        auxRS, auxCVS, tailS, ptrS, packS);

    unsigned* bufs[3] = {egoA, egoB, egoC};
    const int s_grid   = (USER_NUM + 15) / 16;
    const int adj_grid = (N_NODES + 15) / 16;

    for (int l = 0; l < N_LAYERS; ++l) {
        unsigned* in  = bufs[l % 3];
        unsigned* out = bufs[(l + 1) % 3];
        spmm_s<<<s_grid, BLK, 0, stream>>>(ptrS, packS, (const uint4*)in, (uint4*)hu);
        if (l < N_LAYERS - 1) {
            spmm_adj<false><<<adj_grid, BLK, 0, stream>>>(
                ptrA, packA, (const uint4*)hu, (const uint4*)in, (uint4*)out,
                nullptr, nullptr, nullptr, nullptr, nullptr);
        } else {
            // e1 = egoB (layer-0 out), e2 = egoC (layer-1 out); e3 kept in f32
            // accumulators and fused straight into the final average.
            spmm_adj<true><<<adj_grid, BLK, 0, stream>>>(
                ptrA, packA, (const uint4*)hu, (const uint4*)in, nullptr,
                (const uint4*)egoB, (const uint4*)egoC, user_emb, item_emb, acc);
        }
    }
}